// Round 10
// baseline (178.346 us; speedup 1.0000x reference)
//
#include <hip/hip_runtime.h>
#include <math.h>

#define BB 2
#define NN 512
#define DD 32
#define HH 64
#define JT 2
#define NBLK1 (BB*NN*JT)         // 2048 blocks: (b, i, jt)

// ws layout (float offsets)
#define MF_OFF  0                        // 0.5*M^T A-frags: lt(4)*kh(2)*64*8 = 4096 halves = 2048 fl
#define WF_OFF  (MF_OFF + 2048)          // 0.25*Ws1^T A-frags: lt(4)*64*8 = 2048 halves = 1024 fl
#define W1F_OFF (WF_OFF + 1024)          // W1/b1 B-side table: 192 halves (pad 128 fl)
#define ST2_OFF (W1F_OFF + 128)          // per-(b,i,jt) {m, s}: 2048*2 = 4096
#define AR_OFF  (ST2_OFF + 4096)         // per-(b,i,jt) Arow[64]: 2048*64 = 131072
#define TK_OFF  (AR_OFF + 131072)        // ticket (int, 1 slot)

typedef _Float16 half8 __attribute__((ext_vector_type(8)));
typedef float    f32x4 __attribute__((ext_vector_type(4)));

__device__ __forceinline__ half8 h8splat(float v) {
    _Float16 h = (_Float16)v;
    half8 r = {h,h,h,h,h,h,h,h};
    return r;
}

__device__ __forceinline__ void invar2(float pix, float piy, float piz,
                                       float pjx, float pjy, float pjz,
                                       float& s, float& cr) {
    s = pix*pjx + piy*pjy + piz*pjz;
    float e12 = pjx*piy - pjy*pix;
    float e13 = pjx*piz - pjz*pix;
    float e23 = pjy*piz - pjz*piy;
    cr = sqrtf(e12*e12 + e13*e13 + e23*e23);
}

// ---------------- prep: A-side fragment tables + ticket ----------------
#define R2 4096                       // 0.5*M^T frag halves
#define R3 2048                       // 0.25*Ws1^T frag halves
#define R4 192                        // W1/b1 table halves
#define PREP_T (R2+R3+R4+1)

__global__ __launch_bounds__(256) void prep(const float* __restrict__ W1,
                                            const float* __restrict__ b1,
                                            const float* __restrict__ W2,
                                            const float* __restrict__ Ws1,
                                            float* __restrict__ ws) {
    int idx = blockIdx.x * 256 + threadIdx.x;
    if (idx < R2) {
        // A-frag for h-GEMM: frag f = lt*2+kh; lane holds A[row=l][k],
        // l = lt*16 + (lane&15), k = kh*32 + 8*(lane>>4) + t; value = 0.5*M[k][l], M = W2@Ws1
        int e = idx;
        int t = e & 7, lane = (e >> 3) & 63, f = e >> 9;
        int lt = f >> 1, kh = f & 1;
        int k = kh*32 + 8*(lane >> 4) + t;
        int l = lt*16 + (lane & 15);
        float acc = 0.f;
        #pragma unroll
        for (int d = 0; d < DD; d++) acc += W2[k*DD + d] * Ws1[d*HH + l];
        ((_Float16*)(ws + MF_OFF))[e] = (_Float16)(0.5f * acc);
    } else if (idx < R2+R3) {
        // A-frag for v-GEMM: frag lt; lane holds A[row=l][d], d = 8*(lane>>4)+t,
        // l = lt*16+(lane&15); value = 0.25*Ws1[d][l]
        int e = idx - R2;
        int t = e & 7, lane = (e >> 3) & 63, lt = e >> 9;
        int d = 8*(lane >> 4) + t;
        int l = lt*16 + (lane & 15);
        ((_Float16*)(ws + WF_OFF))[e] = (_Float16)(0.25f * Ws1[d*HH + l]);
    } else if (idx < R2+R3+R4) {
        // W1/b1 table: e = ((arr*2+kh)*4+g)*8+t, k = kh*32+8g+t
        int e = idx - R2 - R3;
        int t = e & 7, rest = e >> 3;
        int g = rest & 3, kh = (rest >> 2) & 1, arr = rest >> 3;
        int k = kh*32 + 8*g + t;
        float v = (arr == 0) ? W1[k] : (arr == 1) ? W1[HH + k] : b1[k];
        ((_Float16*)(ws + W1F_OFF))[e] = (_Float16)v;
    } else if (idx < PREP_T) {
        *(int*)(ws + TK_OFF) = 0;
    }
}

// ---------------- pass1: swapped-operand scores + last-block fused final ----------------
// block = (b, i, jt). 4 waves; wave w owns j in [jt*256+w*64, +64); lane (g,lr): j = ..+rf*16+lr.
__global__ __launch_bounds__(256, 2) void pass1(const float* __restrict__ pos,
                                                const float* __restrict__ values,
                                                const float* __restrict__ W2,
                                                const float* __restrict__ b2,
                                                const float* __restrict__ bs1,
                                                const float* __restrict__ Ws2,
                                                const float* __restrict__ bs2,
                                                float* __restrict__ ws,
                                                float* __restrict__ out) {
    __shared__ float lms[4][2];
    __shared__ float Aw[4][HH];
    __shared__ int lastf;
    int blk = blockIdx.x;
    int jt = blk & 1;
    int i  = (blk >> 1) & (NN-1);
    int b  = blk >> 10;
    int tid = threadIdx.x;
    int w    = tid >> 6;
    int lane = tid & 63;
    int g    = lane >> 4;
    int lr   = lane & 15;

    // A-side fragments (global, L2-hit, coalesced 16B/lane)
    const half8* mf8 = (const half8*)(ws + MF_OFF);
    const half8* wf8 = (const half8*)(ws + WF_OFF);
    half8 AfM[4][2], AfW[4];
    #pragma unroll
    for (int lt = 0; lt < 4; lt++) {
        AfM[lt][0] = mf8[(lt*2 + 0)*64 + lane];
        AfM[lt][1] = mf8[(lt*2 + 1)*64 + lane];
        AfW[lt]    = wf8[lt*64 + lane];
    }
    const half8* w1f8 = (const half8*)(ws + W1F_OFF);
    half8 W1a[2], W1b[2], B1f[2];
    #pragma unroll
    for (int kh = 0; kh < 2; kh++) {
        W1a[kh] = w1f8[(0*2 + kh)*4 + g];
        W1b[kh] = w1f8[(1*2 + kh)*4 + g];
        B1f[kh] = w1f8[(2*2 + kh)*4 + g];
    }

    // per-lane l-vectors: l = lt*16 + 4g + r
    float ws2g[16], bs1g[16];
    #pragma unroll
    for (int lt = 0; lt < 4; lt++)
        #pragma unroll
        for (int r = 0; r < 4; r++) {
            int l = lt*16 + 4*g + r;
            ws2g[lt*4+r] = Ws2[l];
            bs1g[lt*4+r] = bs1[l];
        }

    // viplus[d] = v_i[d] + 2*b2[d] for the lane's d-slice (d = 8g+t)
    float vip[8];
    {
        const float* vi = values + (size_t)(b*NN + i)*DD + 8*g;
        float4 a = *(const float4*)vi;
        float4 c = *(const float4*)(vi + 4);
        const float* b2s = b2 + 8*g;
        float4 ba = *(const float4*)b2s;
        float4 bc = *(const float4*)(b2s + 4);
        vip[0]=a.x+2.f*ba.x; vip[1]=a.y+2.f*ba.y; vip[2]=a.z+2.f*ba.z; vip[3]=a.w+2.f*ba.w;
        vip[4]=c.x+2.f*bc.x; vip[5]=c.y+2.f*bc.y; vip[6]=c.z+2.f*bc.z; vip[7]=c.w+2.f*bc.w;
    }

    float pix = pos[(b*NN+i)*3+0], piy = pos[(b*NN+i)*3+1], piz = pos[(b*NN+i)*3+2];
    float bs2v = bs2[0];
    half8 z8 = h8splat(0.f);

    half8 bh0[4], bh1[4];     // retained h (B-operand) per rf
    float x[4];               // lane's own scores
    float m_l = -INFINITY, s_l = 0.f;

    #pragma unroll
    for (int rf = 0; rf < 4; rf++) {
        int j = jt*256 + w*64 + rf*16 + lr;
        float pjx = pos[(b*NN+j)*3+0], pjy = pos[(b*NN+j)*3+1], pjz = pos[(b*NN+j)*3+2];
        float s, cr;
        invar2(pix,piy,piz,pjx,pjy,pjz,s,cr);
        half8 s8 = h8splat(s), c8 = h8splat(cr);
        bh0[rf] = __builtin_elementwise_max(W1a[0]*s8 + W1b[0]*c8 + B1f[0], z8);
        bh1[rf] = __builtin_elementwise_max(W1a[1]*s8 + W1b[1]*c8 + B1f[1], z8);

        // B-operand v-part: v_j + viplus, f16
        const float* vj = values + (size_t)(b*NN + j)*DD + 8*g;
        float4 va = *(const float4*)vj;
        float4 vb = *(const float4*)(vj + 4);
        half8 Bv;
        Bv[0]=(_Float16)(va.x+vip[0]); Bv[1]=(_Float16)(va.y+vip[1]);
        Bv[2]=(_Float16)(va.z+vip[2]); Bv[3]=(_Float16)(va.w+vip[3]);
        Bv[4]=(_Float16)(vb.x+vip[4]); Bv[5]=(_Float16)(vb.y+vip[5]);
        Bv[6]=(_Float16)(vb.z+vip[6]); Bv[7]=(_Float16)(vb.w+vip[7]);

        // pre^T[l][j]: 4 l-tiles, acc init = bs1
        float xp = 0.f;
        #pragma unroll
        for (int lt = 0; lt < 4; lt++) {
            f32x4 c = {bs1g[lt*4+0], bs1g[lt*4+1], bs1g[lt*4+2], bs1g[lt*4+3]};
            c = __builtin_amdgcn_mfma_f32_16x16x32_f16(AfM[lt][0], bh0[rf], c, 0, 0, 0);
            c = __builtin_amdgcn_mfma_f32_16x16x32_f16(AfM[lt][1], bh1[rf], c, 0, 0, 0);
            c = __builtin_amdgcn_mfma_f32_16x16x32_f16(AfW[lt],    Bv,      c, 0, 0, 0);
            xp += fmaxf(c[0], 0.f)*ws2g[lt*4+0];
            xp += fmaxf(c[1], 0.f)*ws2g[lt*4+1];
            xp += fmaxf(c[2], 0.f)*ws2g[lt*4+2];
            xp += fmaxf(c[3], 0.f)*ws2g[lt*4+3];
        }
        // sum over the 4 g-groups (each held 16 of 64 l's)
        xp += __shfl_xor(xp, 16);
        xp += __shfl_xor(xp, 32);
        float xs = xp + bs2v;
        x[rf] = xs;
        // per-lane online (m,s) over own scores
        float nm = fmaxf(m_l, xs);
        s_l = s_l*__expf(m_l - nm) + __expf(xs - nm);
        m_l = nm;
    }

    // wave (m,s): merge 16 lr slots (g-dups identical)
    #pragma unroll
    for (int off = 1; off < 16; off <<= 1) {
        float om = __shfl_xor(m_l, off);
        float os = __shfl_xor(s_l, off);
        float nm = fmaxf(m_l, om);
        s_l = s_l*__expf(m_l - nm) + os*__expf(om - nm);
        m_l = nm;
    }
    if (lane == 0) { lms[w][0] = m_l; lms[w][1] = s_l; }
    __syncthreads();

    // block stats
    float m0 = lms[0][0], m1 = lms[1][0], m2 = lms[2][0], m3 = lms[3][0];
    float mB = fmaxf(fmaxf(m0, m1), fmaxf(m2, m3));
    float sB = lms[0][1]*__expf(m0 - mB) + lms[1][1]*__expf(m1 - mB)
             + lms[2][1]*__expf(m2 - mB) + lms[3][1]*__expf(m3 - mB);
    if (tid == 0) {
        ws[ST2_OFF + blk*2]     = mB;
        ws[ST2_OFF + blk*2 + 1] = sB;
    }

    // phase 3: lane accumulates A over its own 4 j's for its 16 k's (k = kh*32+8g+t)
    float Ak[16];
    #pragma unroll
    for (int t = 0; t < 16; t++) Ak[t] = 0.f;
    #pragma unroll
    for (int rf = 0; rf < 4; rf++) {
        float wgt = __expf(x[rf] - mB);
        #pragma unroll
        for (int t = 0; t < 8; t++) {
            Ak[t]   = fmaf(wgt, (float)bh0[rf][t], Ak[t]);
            Ak[8+t] = fmaf(wgt, (float)bh1[rf][t], Ak[8+t]);
        }
    }
    // reduce over the 16 lr lanes
    #pragma unroll
    for (int t = 0; t < 16; t++) {
        #pragma unroll
        for (int off = 1; off < 16; off <<= 1) Ak[t] += __shfl_xor(Ak[t], off);
    }
    if (lr == 0) {
        #pragma unroll
        for (int t = 0; t < 8; t++) {
            Aw[w][8*g + t]      = Ak[t];
            Aw[w][32 + 8*g + t] = Ak[8+t];
        }
    }
    __syncthreads();
    if (tid < HH)
        ws[AR_OFF + (size_t)blk*HH + tid] = Aw[0][tid] + Aw[1][tid] + Aw[2][tid] + Aw[3][tid];

    // ---- ticket: last block runs the global reduce + output ----
    __threadfence();
    __syncthreads();
    if (tid == 0) {
        int old = atomicAdd((int*)(ws + TK_OFF), 1);
        lastf = (old == NBLK1 - 1);
    }
    __syncthreads();
    if (!lastf) return;
    __threadfence();

    __shared__ float red[8];
    __shared__ float MS[2];
    __shared__ float wfb[NN*JT];
    __shared__ float csh[NN];
    __shared__ float vs8[8][DD];
    __shared__ float as4[4][HH];
    __shared__ float Ash[HH];

    for (int bo = 0; bo < BB; bo++) {
        const float* st2 = ws + ST2_OFF + (size_t)bo*NN*JT*2;   // 1024 (m,s) pairs

        // global (M, S)
        {
            float m = -INFINITY, s = 0.f;
            #pragma unroll
            for (int q = 0; q < 4; q++) {
                int p = tid + q*256;
                float pm = st2[p*2], ps = st2[p*2+1];
                float nm = fmaxf(m, pm);
                s = s*__expf(m - nm) + ps*__expf(pm - nm);
                m = nm;
            }
            for (int off = 1; off < 64; off <<= 1) {
                float om = __shfl_xor(m, off);
                float os = __shfl_xor(s, off);
                float nm = fmaxf(m, om);
                s = s*__expf(m - nm) + os*__expf(om - nm);
                m = nm;
            }
            if (lane == 0) { red[w*2] = m; red[w*2+1] = s; }
        }
        __syncthreads();
        if (tid == 0) {
            float M0 = red[0], S0 = red[1];
            #pragma unroll
            for (int q = 1; q < 4; q++) {
                float nm = fmaxf(M0, red[q*2]);
                S0 = S0*__expf(M0 - nm) + red[q*2+1]*__expf(red[q*2] - nm);
                M0 = nm;
            }
            MS[0] = M0; MS[1] = 1.f / S0;
        }
        __syncthreads();
        float M = MS[0], invS = MS[1];

        // per-segment weights
        #pragma unroll
        for (int q = 0; q < 4; q++) {
            int p = tid + q*256;
            wfb[p] = __expf(st2[p*2] - M) * invS;
        }
        __syncthreads();
        // cs_i = sum_jt s_p * wf[p]   (row sums == col sums by symmetry)
        #pragma unroll
        for (int q = 0; q < 2; q++) {
            int ii = tid + q*256;
            csh[ii] = st2[(2*ii)*2+1]*wfb[2*ii] + st2[(2*ii+1)*2+1]*wfb[2*ii+1];
        }
        __syncthreads();

        // vsum[d] = sum_i cs_i * v[i][d]
        {
            int d = tid & 31, sl = tid >> 5;
            float v = 0.f;
            for (int ii = sl*64; ii < sl*64 + 64; ii++)
                v += csh[ii] * values[(size_t)(bo*NN + ii)*DD + d];
            vs8[sl][d] = v;
        }
        // A[k] = sum_p AR[p][k] * wf[p]
        {
            int k = tid & 63, sl = tid >> 6;
            const float* ar = ws + AR_OFF + (size_t)bo*NN*JT*HH;
            float a = 0.f;
            for (int p = sl*256; p < sl*256 + 256; p++)
                a += ar[(size_t)p*HH + k] * wfb[p];
            as4[sl][k] = a;
        }
        __syncthreads();
        if (tid < HH) Ash[tid] = as4[0][tid] + as4[1][tid] + as4[2][tid] + as4[3][tid];
        __syncthreads();
        if (tid < DD) {
            float vsum = 0.f;
            #pragma unroll
            for (int q = 0; q < 8; q++) vsum += vs8[q][tid];
            float aw = 0.f;
            #pragma unroll
            for (int k = 0; k < HH; k++) aw += Ash[k] * W2[k*DD + tid];
            out[bo*DD + tid] = 0.5f*b2[tid] + 0.5f*aw + 0.5f*vsum;
        }
        __syncthreads();
    }
}

extern "C" void kernel_launch(void* const* d_in, const int* in_sizes, int n_in,
                              void* d_out, int out_size, void* d_ws, size_t ws_size,
                              hipStream_t stream) {
    (void)in_sizes; (void)n_in; (void)out_size; (void)ws_size;
    const float* pos    = (const float*)d_in[0];
    const float* values = (const float*)d_in[1];
    const float* W1     = (const float*)d_in[2];
    const float* b1     = (const float*)d_in[3];
    const float* W2     = (const float*)d_in[4];
    const float* b2     = (const float*)d_in[5];
    const float* Ws1    = (const float*)d_in[6];
    const float* bs1    = (const float*)d_in[7];
    const float* Ws2    = (const float*)d_in[8];
    const float* bs2    = (const float*)d_in[9];
    float* ws  = (float*)d_ws;
    float* out = (float*)d_out;

    prep  <<<(PREP_T + 255)/256, 256, 0, stream>>>(W1, b1, W2, Ws1, ws);
    pass1 <<<NBLK1, 256, 0, stream>>>(pos, values, W2, b2, bs1, Ws2, bs2, ws, out);
}

// Round 11
// 42.348 us; speedup vs baseline: 4.2114x; 4.2114x over previous
//
#include <hip/hip_runtime.h>
#include <math.h>

#define BB 2
#define NN 512
#define DD 32
#define HH 64
#define JT 2
#define NBLK1 (BB*NN*JT)         // 2048 blocks: (b, i, jt)

// ws layout (float offsets)
#define MF_OFF  0                        // 0.5*M^T A-frags: lt(4)*kh(2)*64*8 = 4096 halves = 2048 fl
#define WF_OFF  (MF_OFF + 2048)          // 0.25*Ws1^T A-frags: lt(4)*64*8 = 2048 halves = 1024 fl
#define W1F_OFF (WF_OFF + 1024)          // W1/b1 B-side table: 192 halves (pad 128 fl)
#define ST2_OFF (W1F_OFF + 128)          // per-(b,i,jt) {m, s}: 2048*2 = 4096
#define AR_OFF  (ST2_OFF + 4096)         // per-(b,i,jt) Arow[64]: 2048*64 = 131072

typedef _Float16 half8 __attribute__((ext_vector_type(8)));
typedef float    f32x4 __attribute__((ext_vector_type(4)));

__device__ __forceinline__ half8 h8splat(float v) {
    _Float16 h = (_Float16)v;
    half8 r = {h,h,h,h,h,h,h,h};
    return r;
}

__device__ __forceinline__ void invar2(float pix, float piy, float piz,
                                       float pjx, float pjy, float pjz,
                                       float& s, float& cr) {
    s = pix*pjx + piy*pjy + piz*pjz;
    float e12 = pjx*piy - pjy*pix;
    float e13 = pjx*piz - pjz*pix;
    float e23 = pjy*piz - pjz*piy;
    cr = sqrtf(e12*e12 + e13*e13 + e23*e23);
}

// ---------------- prep: A-side fragment tables (transposed roles) ----------------
#define R2 4096                       // 0.5*M^T frag halves
#define R3 2048                       // 0.25*Ws1^T frag halves
#define R4 192                        // W1/b1 table halves
#define PREP_T (R2+R3+R4)

__global__ __launch_bounds__(256) void prep(const float* __restrict__ W1,
                                            const float* __restrict__ b1,
                                            const float* __restrict__ W2,
                                            const float* __restrict__ Ws1,
                                            float* __restrict__ ws) {
    int idx = blockIdx.x * 256 + threadIdx.x;
    if (idx < R2) {
        // A-frag for h-GEMM: frag f = lt*2+kh; lane holds A[row=l][k],
        // l = lt*16 + (lane&15), k = kh*32 + 8*(lane>>4) + t; value = 0.5*M[k][l], M = W2@Ws1
        int e = idx;
        int t = e & 7, lane = (e >> 3) & 63, f = e >> 9;
        int lt = f >> 1, kh = f & 1;
        int k = kh*32 + 8*(lane >> 4) + t;
        int l = lt*16 + (lane & 15);
        float acc = 0.f;
        #pragma unroll
        for (int d = 0; d < DD; d++) acc += W2[k*DD + d] * Ws1[d*HH + l];
        ((_Float16*)(ws + MF_OFF))[e] = (_Float16)(0.5f * acc);
    } else if (idx < R2+R3) {
        // A-frag for v-GEMM: frag lt; lane holds A[row=l][d], d = 8*(lane>>4)+t,
        // l = lt*16+(lane&15); value = 0.25*Ws1[d][l]
        int e = idx - R2;
        int t = e & 7, lane = (e >> 3) & 63, lt = e >> 9;
        int d = 8*(lane >> 4) + t;
        int l = lt*16 + (lane & 15);
        ((_Float16*)(ws + WF_OFF))[e] = (_Float16)(0.25f * Ws1[d*HH + l]);
    } else if (idx < R2+R3+R4) {
        // W1/b1 table: e = ((arr*2+kh)*4+g)*8+t, k = kh*32+8g+t
        int e = idx - R2 - R3;
        int t = e & 7, rest = e >> 3;
        int g = rest & 3, kh = (rest >> 2) & 1, arr = rest >> 3;
        int k = kh*32 + 8*g + t;
        float v = (arr == 0) ? W1[k] : (arr == 1) ? W1[HH + k] : b1[k];
        ((_Float16*)(ws + W1F_OFF))[e] = (_Float16)v;
    }
}

// ---------------- pass1: swapped-operand scores, lane-owns-j, DS-minimal ----------------
// block = (b, i, jt). 4 waves; wave w owns j in [jt*256+w*64, +64); lane (g,lr): j = ..+rf*16+lr.
__global__ __launch_bounds__(256, 2) void pass1(const float* __restrict__ pos,
                                                const float* __restrict__ values,
                                                const float* __restrict__ b2,
                                                const float* __restrict__ bs1,
                                                const float* __restrict__ Ws2,
                                                const float* __restrict__ bs2,
                                                float* __restrict__ ws) {
    __shared__ float lms[4][2];
    __shared__ float Aw[4][HH];
    int blk = blockIdx.x;
    int jt = blk & 1;
    int i  = (blk >> 1) & (NN-1);
    int b  = blk >> 10;
    int tid = threadIdx.x;
    int w    = tid >> 6;
    int lane = tid & 63;
    int g    = lane >> 4;
    int lr   = lane & 15;

    // A-side fragments (global, L2-hit, coalesced 16B/lane)
    const half8* mf8 = (const half8*)(ws + MF_OFF);
    const half8* wf8 = (const half8*)(ws + WF_OFF);
    half8 AfM[4][2], AfW[4];
    #pragma unroll
    for (int lt = 0; lt < 4; lt++) {
        AfM[lt][0] = mf8[(lt*2 + 0)*64 + lane];
        AfM[lt][1] = mf8[(lt*2 + 1)*64 + lane];
        AfW[lt]    = wf8[lt*64 + lane];
    }
    const half8* w1f8 = (const half8*)(ws + W1F_OFF);
    half8 W1a[2], W1b[2], B1f[2];
    #pragma unroll
    for (int kh = 0; kh < 2; kh++) {
        W1a[kh] = w1f8[(0*2 + kh)*4 + g];
        W1b[kh] = w1f8[(1*2 + kh)*4 + g];
        B1f[kh] = w1f8[(2*2 + kh)*4 + g];
    }

    // per-lane l-vectors: l = lt*16 + 4g + r
    float ws2g[16], bs1g[16];
    #pragma unroll
    for (int lt = 0; lt < 4; lt++)
        #pragma unroll
        for (int r = 0; r < 4; r++) {
            int l = lt*16 + 4*g + r;
            ws2g[lt*4+r] = Ws2[l];
            bs1g[lt*4+r] = bs1[l];
        }

    // viplus[d] = v_i[d] + 2*b2[d] for the lane's d-slice (d = 8g+t)
    float vip[8];
    {
        const float* vi = values + (size_t)(b*NN + i)*DD + 8*g;
        float4 a = *(const float4*)vi;
        float4 c = *(const float4*)(vi + 4);
        const float* b2s = b2 + 8*g;
        float4 ba = *(const float4*)b2s;
        float4 bc = *(const float4*)(b2s + 4);
        vip[0]=a.x+2.f*ba.x; vip[1]=a.y+2.f*ba.y; vip[2]=a.z+2.f*ba.z; vip[3]=a.w+2.f*ba.w;
        vip[4]=c.x+2.f*bc.x; vip[5]=c.y+2.f*bc.y; vip[6]=c.z+2.f*bc.z; vip[7]=c.w+2.f*bc.w;
    }

    float pix = pos[(b*NN+i)*3+0], piy = pos[(b*NN+i)*3+1], piz = pos[(b*NN+i)*3+2];
    float bs2v = bs2[0];
    half8 z8 = h8splat(0.f);

    half8 bh0[4], bh1[4];     // retained h (B-operand) per rf
    float x[4];               // lane's own scores
    float m_l = -INFINITY, s_l = 0.f;

    #pragma unroll
    for (int rf = 0; rf < 4; rf++) {
        int j = jt*256 + w*64 + rf*16 + lr;
        float pjx = pos[(b*NN+j)*3+0], pjy = pos[(b*NN+j)*3+1], pjz = pos[(b*NN+j)*3+2];
        float s, cr;
        invar2(pix,piy,piz,pjx,pjy,pjz,s,cr);
        half8 s8 = h8splat(s), c8 = h8splat(cr);
        bh0[rf] = __builtin_elementwise_max(W1a[0]*s8 + W1b[0]*c8 + B1f[0], z8);
        bh1[rf] = __builtin_elementwise_max(W1a[1]*s8 + W1b[1]*c8 + B1f[1], z8);

        // B-operand v-part: v_j + viplus, f16
        const float* vj = values + (size_t)(b*NN + j)*DD + 8*g;
        float4 va = *(const float4*)vj;
        float4 vb = *(const float4*)(vj + 4);
        half8 Bv;
        Bv[0]=(_Float16)(va.x+vip[0]); Bv[1]=(_Float16)(va.y+vip[1]);
        Bv[2]=(_Float16)(va.z+vip[2]); Bv[3]=(_Float16)(va.w+vip[3]);
        Bv[4]=(_Float16)(vb.x+vip[4]); Bv[5]=(_Float16)(vb.y+vip[5]);
        Bv[6]=(_Float16)(vb.z+vip[6]); Bv[7]=(_Float16)(vb.w+vip[7]);

        // pre^T[l][j]: 4 l-tiles, acc init = bs1
        float xp = 0.f;
        #pragma unroll
        for (int lt = 0; lt < 4; lt++) {
            f32x4 c = {bs1g[lt*4+0], bs1g[lt*4+1], bs1g[lt*4+2], bs1g[lt*4+3]};
            c = __builtin_amdgcn_mfma_f32_16x16x32_f16(AfM[lt][0], bh0[rf], c, 0, 0, 0);
            c = __builtin_amdgcn_mfma_f32_16x16x32_f16(AfM[lt][1], bh1[rf], c, 0, 0, 0);
            c = __builtin_amdgcn_mfma_f32_16x16x32_f16(AfW[lt],    Bv,      c, 0, 0, 0);
            xp += fmaxf(c[0], 0.f)*ws2g[lt*4+0];
            xp += fmaxf(c[1], 0.f)*ws2g[lt*4+1];
            xp += fmaxf(c[2], 0.f)*ws2g[lt*4+2];
            xp += fmaxf(c[3], 0.f)*ws2g[lt*4+3];
        }
        // sum over the 4 g-groups (each held 16 of 64 l's)
        xp += __shfl_xor(xp, 16);
        xp += __shfl_xor(xp, 32);
        float xs = xp + bs2v;
        x[rf] = xs;
        // per-lane online (m,s) over own scores
        float nm = fmaxf(m_l, xs);
        s_l = s_l*__expf(m_l - nm) + __expf(xs - nm);
        m_l = nm;
    }

    // wave (m,s): merge 16 lr slots (g-dups identical)
    #pragma unroll
    for (int off = 1; off < 16; off <<= 1) {
        float om = __shfl_xor(m_l, off);
        float os = __shfl_xor(s_l, off);
        float nm = fmaxf(m_l, om);
        s_l = s_l*__expf(m_l - nm) + os*__expf(om - nm);
        m_l = nm;
    }
    if (lane == 0) { lms[w][0] = m_l; lms[w][1] = s_l; }
    __syncthreads();

    // block stats
    float m0 = lms[0][0], m1 = lms[1][0], m2 = lms[2][0], m3 = lms[3][0];
    float mB = fmaxf(fmaxf(m0, m1), fmaxf(m2, m3));
    float sB = lms[0][1]*__expf(m0 - mB) + lms[1][1]*__expf(m1 - mB)
             + lms[2][1]*__expf(m2 - mB) + lms[3][1]*__expf(m3 - mB);
    if (tid == 0) {
        ws[ST2_OFF + blk*2]     = mB;
        ws[ST2_OFF + blk*2 + 1] = sB;
    }

    // phase 3: lane accumulates A over its own 4 j's for its 16 k's (k = kh*32+8g+t)
    float Ak[16];
    #pragma unroll
    for (int t = 0; t < 16; t++) Ak[t] = 0.f;
    #pragma unroll
    for (int rf = 0; rf < 4; rf++) {
        float wgt = __expf(x[rf] - mB);
        #pragma unroll
        for (int t = 0; t < 8; t++) {
            Ak[t]   = fmaf(wgt, (float)bh0[rf][t], Ak[t]);
            Ak[8+t] = fmaf(wgt, (float)bh1[rf][t], Ak[8+t]);
        }
    }
    // reduce over the 16 lr lanes
    #pragma unroll
    for (int t = 0; t < 16; t++) {
        #pragma unroll
        for (int off = 1; off < 16; off <<= 1) Ak[t] += __shfl_xor(Ak[t], off);
    }
    if (lr == 0) {
        #pragma unroll
        for (int t = 0; t < 8; t++) {
            Aw[w][8*g + t]      = Ak[t];
            Aw[w][32 + 8*g + t] = Ak[8+t];
        }
    }
    __syncthreads();
    if (tid < HH)
        ws[AR_OFF + (size_t)blk*HH + tid] = Aw[0][tid] + Aw[1][tid] + Aw[2][tid] + Aw[3][tid];
}

// ---------------- finalk: global softmax reduce + combine (one block per batch) ----------------
__global__ __launch_bounds__(256) void finalk(const float* __restrict__ values,
                                              const float* __restrict__ W2,
                                              const float* __restrict__ b2,
                                              const float* __restrict__ ws,
                                              float* __restrict__ out) {
    __shared__ float red[8];
    __shared__ float MS[2];
    __shared__ float wf[NN*JT];    // 4 KB
    __shared__ float csh[NN];      // 2 KB
    __shared__ float vs8[8][DD];
    __shared__ float as4[4][HH];
    __shared__ float Ash[HH];
    int b = blockIdx.x;
    int tid = threadIdx.x;
    int w = tid >> 6, lane = tid & 63;
    const float* st2 = ws + ST2_OFF + (size_t)b*NN*JT*2;   // 1024 (m,s) pairs

    // phase 1: global (M, S)
    {
        float m = -INFINITY, s = 0.f;
        #pragma unroll
        for (int q = 0; q < 4; q++) {
            int p = tid + q*256;
            float pm = st2[p*2], ps = st2[p*2+1];
            float nm = fmaxf(m, pm);
            s = s*__expf(m - nm) + ps*__expf(pm - nm);
            m = nm;
        }
        for (int off = 1; off < 64; off <<= 1) {
            float om = __shfl_xor(m, off);
            float os = __shfl_xor(s, off);
            float nm = fmaxf(m, om);
            s = s*__expf(m - nm) + os*__expf(om - nm);
            m = nm;
        }
        if (lane == 0) { red[w*2] = m; red[w*2+1] = s; }
    }
    __syncthreads();
    if (tid == 0) {
        float M0 = red[0], S0 = red[1];
        #pragma unroll
        for (int q = 1; q < 4; q++) {
            float nm = fmaxf(M0, red[q*2]);
            S0 = S0*__expf(M0 - nm) + red[q*2+1]*__expf(red[q*2] - nm);
            M0 = nm;
        }
        MS[0] = M0; MS[1] = 1.f / S0;
    }
    __syncthreads();
    float M = MS[0], invS = MS[1];

    // phase 2: per-segment weights wf[p] = exp(m_p - M) / S
    #pragma unroll
    for (int q = 0; q < 4; q++) {
        int p = tid + q*256;
        wf[p] = __expf(st2[p*2] - M) * invS;
    }
    __syncthreads();
    // cs_i = sum_jt s_p * wf[p]   (row sums == col sums by symmetry)
    #pragma unroll
    for (int q = 0; q < 2; q++) {
        int i = tid + q*256;
        csh[i] = st2[(2*i)*2+1]*wf[2*i] + st2[(2*i+1)*2+1]*wf[2*i+1];
    }
    __syncthreads();

    // vsum[d] = sum_i cs_i * v[i][d]
    {
        int d = tid & 31, sl = tid >> 5;
        float v = 0.f;
        for (int i = sl*64; i < sl*64 + 64; i++)
            v += csh[i] * values[(size_t)(b*NN + i)*DD + d];
        vs8[sl][d] = v;
    }
    // A[k] = sum_p AR[p][k] * wf[p]
    {
        int k = tid & 63, sl = tid >> 6;
        const float* ar = ws + AR_OFF + (size_t)b*NN*JT*HH;
        float a = 0.f;
        for (int p = sl*256; p < sl*256 + 256; p++)
            a += ar[(size_t)p*HH + k] * wf[p];
        as4[sl][k] = a;
    }
    __syncthreads();
    if (tid < HH) Ash[tid] = as4[0][tid] + as4[1][tid] + as4[2][tid] + as4[3][tid];
    __syncthreads();
    if (tid < DD) {
        float vsum = 0.f;
        #pragma unroll
        for (int q = 0; q < 8; q++) vsum += vs8[q][tid];
        float aw = 0.f;
        #pragma unroll
        for (int k = 0; k < HH; k++) aw += Ash[k] * W2[k*DD + tid];
        out[b*DD + tid] = 0.5f*b2[tid] + 0.5f*aw + 0.5f*vsum;
    }
}

extern "C" void kernel_launch(void* const* d_in, const int* in_sizes, int n_in,
                              void* d_out, int out_size, void* d_ws, size_t ws_size,
                              hipStream_t stream) {
    (void)in_sizes; (void)n_in; (void)out_size; (void)ws_size;
    const float* pos    = (const float*)d_in[0];
    const float* values = (const float*)d_in[1];
    const float* W1     = (const float*)d_in[2];
    const float* b1     = (const float*)d_in[3];
    const float* W2     = (const float*)d_in[4];
    const float* b2     = (const float*)d_in[5];
    const float* Ws1    = (const float*)d_in[6];
    const float* bs1    = (const float*)d_in[7];
    const float* Ws2    = (const float*)d_in[8];
    const float* bs2    = (const float*)d_in[9];
    float* ws  = (float*)d_ws;
    float* out = (float*)d_out;

    prep  <<<(PREP_T + 255)/256, 256, 0, stream>>>(W1, b1, W2, Ws1, ws);
    pass1 <<<NBLK1, 256, 0, stream>>>(pos, values, b2, bs1, Ws2, bs2, ws);
    finalk<<<BB, 256, 0, stream>>>(values, W2, b2, ws, out);
}